// Round 1
// baseline (694.809 us; speedup 1.0000x reference)
//
#include <hip/hip_runtime.h>

// ---------------------------------------------------------------------------
// FDA_Module_21500606283969: out = x + MLP(LN(x))
//   LN(D=1024) -> W1(1024x512)+b1,gelu -> W2(512x512)+b2,gelu
//   -> W3(512x256)+b3,gelu -> W4(256x1024)+b4, + x residual
// Strategy: bf16 MFMA GEMMs (16x16x32), weights pre-transposed to [N][K] bf16,
// LN folded into GEMM1 epilogue via per-row (mu, rstd) + per-col (u1, c1).
// ---------------------------------------------------------------------------

typedef short short8 __attribute__((ext_vector_type(8)));
typedef float floatx4 __attribute__((ext_vector_type(4)));

__device__ __forceinline__ unsigned short f2bf(float f) {
    union { float f; unsigned int u; } a; a.f = f;
    unsigned int u = a.u;
    return (unsigned short)((u + 0x7FFFu + ((u >> 16) & 1u)) >> 16);
}

__device__ __forceinline__ float gelu_exact(float v) {
    return 0.5f * v * (1.0f + erff(v * 0.70710678118654752f));
}

// ---- weight transpose+convert: Wt[n*K+k] = bf16(W[k*N+n] * (scale?scale[k]:1))
__global__ __launch_bounds__(256) void conv_w_kernel(
    const float* __restrict__ W, const float* __restrict__ scale,
    unsigned short* __restrict__ Wt, int K, int N) {
    int t = blockIdx.x * 256 + threadIdx.x;   // t = k*N + n (coalesced read)
    if (t >= K * N) return;
    int k = t / N, n = t - k * N;
    float v = W[t];
    if (scale) v *= scale[k];
    Wt[(size_t)n * K + k] = f2bf(v);
}

// ---- u1[n] = sum_k gamma[k]*W1[k][n];  c1[n] = sum_k beta[k]*W1[k][n] + b1[n]
__global__ __launch_bounds__(256) void u1c1_kernel(
    const float* __restrict__ W1, const float* __restrict__ gamma,
    const float* __restrict__ beta, const float* __restrict__ b1,
    float* __restrict__ u1, float* __restrict__ c1, int K, int N) {
    int n = blockIdx.x * 256 + threadIdx.x;
    if (n >= N) return;
    float u = 0.f, c = 0.f;
    for (int k = 0; k < K; k++) {
        float w = W1[(size_t)k * N + n];
        u += gamma[k] * w;
        c += beta[k] * w;
    }
    u1[n] = u;
    c1[n] = c + b1[n];
}

// ---- per-row LN stats: mu, rstd.  One wave per row, D=1024.
__global__ __launch_bounds__(256) void ln_stats_kernel(
    const float* __restrict__ x, float* __restrict__ mu, float* __restrict__ rs) {
    const int D = 1024;
    int row = blockIdx.x * 4 + (threadIdx.x >> 6);
    int lane = threadIdx.x & 63;
    const float4* xr = (const float4*)(x + (size_t)row * D);
    float s = 0.f, ss = 0.f;
#pragma unroll
    for (int i = 0; i < 4; i++) {
        float4 v = xr[lane + 64 * i];
        s  += v.x + v.y + v.z + v.w;
        ss += v.x * v.x + v.y * v.y + v.z * v.z + v.w * v.w;
    }
#pragma unroll
    for (int off = 32; off; off >>= 1) {
        s  += __shfl_xor(s, off);
        ss += __shfl_xor(ss, off);
    }
    if (lane == 0) {
        float m = s * (1.0f / 1024.0f);
        mu[row] = m;
        rs[row] = rsqrtf(ss * (1.0f / 1024.0f) - m * m + 1e-5f);
    }
}

// ---- GEMM: C[M,N] = A[M,K] * Bt[N,K]^T, 128x128 tile, BK=32, 256 thr / 4 waves
// EPMODE 0: LN-corrected + gelu -> bf16   (A is fp32, converted in staging)
// EPMODE 1: +bias, gelu -> bf16
// EPMODE 2: +bias, +residual(fp32) -> fp32
template <int EPMODE, bool AF32>
__global__ __launch_bounds__(256) void gemm_kernel(
    const void* __restrict__ Aptr, const unsigned short* __restrict__ Bt,
    void* __restrict__ Out, int N, int K,
    const float* __restrict__ bias,   // EP0: c1
    const float* __restrict__ u1,     // EP0 only
    const float* __restrict__ mu,     // EP0 only
    const float* __restrict__ rs,     // EP0 only
    const float* __restrict__ resid)  // EP2 only
{
    constexpr int BM = 128, BN = 128, BK = 32;
    __shared__ unsigned short As[BM][BK];
    __shared__ unsigned short Bs[BN][BK];

    const int tid  = threadIdx.x;
    const int wave = tid >> 6;
    const int lane = tid & 63;
    const int q    = lane >> 4;   // quad 0..3
    const int l16  = lane & 15;
    const int wm   = wave & 1;    // wave row-half
    const int wn   = wave >> 1;   // wave col-half
    const int m0   = blockIdx.y * BM;
    const int n0   = blockIdx.x * BN;

    floatx4 acc[4][4] = {};

    for (int k0 = 0; k0 < K; k0 += BK) {
        // ---- stage A tile (128 x 32 bf16)
        if (AF32) {
            const float* A = (const float*)Aptr;
            int c = tid & 7, r0 = tid >> 3;            // c: float4 chunk, r0: 0..31
#pragma unroll
            for (int i = 0; i < 4; i++) {
                int r = r0 + 32 * i;
                float4 v = *(const float4*)(A + (size_t)(m0 + r) * K + k0 + c * 4);
                unsigned short* dst = &As[r][c * 4];
                dst[0] = f2bf(v.x); dst[1] = f2bf(v.y);
                dst[2] = f2bf(v.z); dst[3] = f2bf(v.w);
            }
        } else {
            const unsigned short* A = (const unsigned short*)Aptr;
            int c = tid & 3, r0 = tid >> 2;            // c: 8-elem chunk, r0: 0..63
#pragma unroll
            for (int i = 0; i < 2; i++) {
                int r = r0 + 64 * i;
                uint4 v = *(const uint4*)(A + (size_t)(m0 + r) * K + k0 + c * 8);
                *(uint4*)&As[r][c * 8] = v;
            }
        }
        // ---- stage Bt tile (128 x 32 bf16), Bt is [N][K] row-major
        {
            int c = tid & 3, r0 = tid >> 2;
#pragma unroll
            for (int i = 0; i < 2; i++) {
                int r = r0 + 64 * i;
                uint4 v = *(const uint4*)(Bt + (size_t)(n0 + r) * K + k0 + c * 8);
                *(uint4*)&Bs[r][c * 8] = v;
            }
        }
        __syncthreads();

        short8 a[4], b[4];
#pragma unroll
        for (int mt = 0; mt < 4; mt++)
            a[mt] = *(const short8*)&As[wm * 64 + mt * 16 + l16][q * 8];
#pragma unroll
        for (int nt = 0; nt < 4; nt++)
            b[nt] = *(const short8*)&Bs[wn * 64 + nt * 16 + l16][q * 8];
#pragma unroll
        for (int mt = 0; mt < 4; mt++)
#pragma unroll
            for (int nt = 0; nt < 4; nt++)
                acc[mt][nt] = __builtin_amdgcn_mfma_f32_16x16x32_bf16(
                    a[mt], b[nt], acc[mt][nt], 0, 0, 0);
        __syncthreads();
    }

    // ---- epilogue: C/D layout col = lane&15, row = quad*4 + reg
#pragma unroll
    for (int mt = 0; mt < 4; mt++) {
#pragma unroll
        for (int r = 0; r < 4; r++) {
            int row = m0 + wm * 64 + mt * 16 + q * 4 + r;
            float rsv = 0.f, muv = 0.f;
            if (EPMODE == 0) { rsv = rs[row]; muv = mu[row]; }
#pragma unroll
            for (int nt = 0; nt < 4; nt++) {
                int col = n0 + wn * 64 + nt * 16 + l16;
                float v = acc[mt][nt][r];
                if constexpr (EPMODE == 0) {
                    v = rsv * (v - muv * u1[col]) + bias[col];
                    v = gelu_exact(v);
                    ((unsigned short*)Out)[(size_t)row * N + col] = f2bf(v);
                } else if constexpr (EPMODE == 1) {
                    v = gelu_exact(v + bias[col]);
                    ((unsigned short*)Out)[(size_t)row * N + col] = f2bf(v);
                } else {
                    v = v + bias[col] + resid[(size_t)row * N + col];
                    ((float*)Out)[(size_t)row * N + col] = v;
                }
            }
        }
    }
}

extern "C" void kernel_launch(void* const* d_in, const int* in_sizes, int n_in,
                              void* d_out, int out_size, void* d_ws, size_t ws_size,
                              hipStream_t stream) {
    const float* x     = (const float*)d_in[0];
    const float* gamma = (const float*)d_in[1];
    const float* beta  = (const float*)d_in[2];
    const float* W1    = (const float*)d_in[3];
    const float* b1    = (const float*)d_in[4];
    const float* W2    = (const float*)d_in[5];
    const float* b2    = (const float*)d_in[6];
    const float* W3    = (const float*)d_in[7];
    const float* b3    = (const float*)d_in[8];
    const float* W4    = (const float*)d_in[9];
    const float* b4    = (const float*)d_in[10];
    float* out = (float*)d_out;

    const int D = 1024, H1 = 512, H2 = 512, H3 = 256;
    const int M = in_sizes[0] / D;   // 32768

    // ---- workspace layout (bytes, all 256-aligned) -------------------------
    char* ws = (char*)d_ws;
    unsigned short* Wt1 = (unsigned short*)(ws + 0);          // 512x1024 bf16, gamma-folded
    unsigned short* Wt2 = (unsigned short*)(ws + 1048576);    // 512x512
    unsigned short* Wt3 = (unsigned short*)(ws + 1572864);    // 256x512
    unsigned short* Wt4 = (unsigned short*)(ws + 1835008);    // 1024x256
    float* u1           = (float*)(ws + 2359296);             // [512]
    float* c1           = (float*)(ws + 2361344);             // [512]
    float* muv          = (float*)(ws + 2363392);             // [M]
    float* rsv          = (float*)(ws + 2494464);             // [M]
    unsigned short* h1  = (unsigned short*)(ws + 2625536);    // M x 512 bf16 (32MB)
    unsigned short* h2  = (unsigned short*)(ws + 36179968);   // M x 512 bf16 (32MB)
    unsigned short* h3  = h1;                                 // alias: h1 dead after G2
    // total: ~69.7 MB

    // ---- weight prep -------------------------------------------------------
    conv_w_kernel<<<(D * H1 + 255) / 256, 256, 0, stream>>>(W1, gamma, Wt1, D,  H1);
    conv_w_kernel<<<(H1 * H2 + 255) / 256, 256, 0, stream>>>(W2, nullptr, Wt2, H1, H2);
    conv_w_kernel<<<(H2 * H3 + 255) / 256, 256, 0, stream>>>(W3, nullptr, Wt3, H2, H3);
    conv_w_kernel<<<(H3 * D + 255) / 256, 256, 0, stream>>>(W4, nullptr, Wt4, H3, D);
    u1c1_kernel<<<(H1 + 255) / 256, 256, 0, stream>>>(W1, gamma, beta, b1, u1, c1, D, H1);

    // ---- LN row stats ------------------------------------------------------
    ln_stats_kernel<<<M / 4, 256, 0, stream>>>(x, muv, rsv);

    // ---- GEMM chain --------------------------------------------------------
    gemm_kernel<0, true ><<<dim3(H1 / 128, M / 128), 256, 0, stream>>>(
        x,  Wt1, h1,  H1, D,  c1, u1, muv, rsv, nullptr);
    gemm_kernel<1, false><<<dim3(H2 / 128, M / 128), 256, 0, stream>>>(
        h1, Wt2, h2,  H2, H1, b2, nullptr, nullptr, nullptr, nullptr);
    gemm_kernel<1, false><<<dim3(H3 / 128, M / 128), 256, 0, stream>>>(
        h2, Wt3, h3,  H3, H2, b3, nullptr, nullptr, nullptr, nullptr);
    gemm_kernel<2, false><<<dim3(D  / 128, M / 128), 256, 0, stream>>>(
        h3, Wt4, out, D,  H3, b4, nullptr, nullptr, nullptr, x);
}

// Round 2
// 471.296 us; speedup vs baseline: 1.4743x; 1.4743x over previous
//
#include <hip/hip_runtime.h>

// ---------------------------------------------------------------------------
// FDA_Module_21500606283969: out = x + MLP(LN(x))
// R2: (a) parallel u1c1 (was 240us @ 2 workgroups -> ~5us),
//     (b) global_load_lds width-16 staging for all GEMM tiles (m97 pattern),
//         enabled by materializing xb = bf16(x) inside ln_stats when ws_size
//         permits; fallback keeps fp32-A staging for GEMM1.
// ---------------------------------------------------------------------------

typedef short short8 __attribute__((ext_vector_type(8)));
typedef float floatx4 __attribute__((ext_vector_type(4)));
typedef unsigned short ushort4v __attribute__((ext_vector_type(4)));

__device__ __forceinline__ unsigned short f2bf(float f) {
    union { float f; unsigned int u; } a; a.f = f;
    unsigned int u = a.u;
    return (unsigned short)((u + 0x7FFFu + ((u >> 16) & 1u)) >> 16);
}

__device__ __forceinline__ float gelu_exact(float v) {
    return 0.5f * v * (1.0f + erff(v * 0.70710678118654752f));
}

// async global->LDS, 16B per lane; LDS dst = wave-uniform base + lane*16
__device__ __forceinline__ void gl_lds16(const unsigned short* g, unsigned short* l) {
    __builtin_amdgcn_global_load_lds(
        (const __attribute__((address_space(1))) void*)g,
        (__attribute__((address_space(3))) void*)l, 16, 0, 0);
}

// ---- weight transpose+convert: Wt[n*K+k] = bf16(W[k*N+n] * (scale?scale[k]:1))
__global__ __launch_bounds__(256) void conv_w_kernel(
    const float* __restrict__ W, const float* __restrict__ scale,
    unsigned short* __restrict__ Wt, int K, int N) {
    int t = blockIdx.x * 256 + threadIdx.x;   // t = k*N + n (coalesced read)
    if (t >= K * N) return;
    int k = t / N, n = t - k * N;
    float v = W[t];
    if (scale) v *= scale[k];
    Wt[(size_t)n * K + k] = f2bf(v);
}

// ---- u1[n]=0 ; c1[n]=b1[n]  (seed for atomic accumulation)
__global__ __launch_bounds__(256) void u1c1_init_kernel(
    const float* __restrict__ b1, float* __restrict__ u1, float* __restrict__ c1,
    int N) {
    int n = blockIdx.x * 256 + threadIdx.x;
    if (n >= N) return;
    u1[n] = 0.f;
    c1[n] = b1[n];
}

// ---- partial u1/c1: block b covers k in [b*16, b*16+16), thread -> cols n, n+256
__global__ __launch_bounds__(256) void u1c1_kernel(
    const float* __restrict__ W1, const float* __restrict__ gamma,
    const float* __restrict__ beta, float* __restrict__ u1,
    float* __restrict__ c1) {
    const int N = 512;
    __shared__ float gs[16], bs[16];
    int n = threadIdx.x;
    int k0 = blockIdx.x * 16;
    if (n < 16) { gs[n] = gamma[k0 + n]; bs[n] = beta[k0 + n]; }
    __syncthreads();
    float ua = 0.f, ca = 0.f, ub = 0.f, cb = 0.f;
#pragma unroll
    for (int i = 0; i < 16; i++) {
        float w0 = W1[(size_t)(k0 + i) * N + n];
        float w1 = W1[(size_t)(k0 + i) * N + n + 256];
        ua += gs[i] * w0; ca += bs[i] * w0;
        ub += gs[i] * w1; cb += bs[i] * w1;
    }
    atomicAdd(&u1[n], ua);       atomicAdd(&c1[n], ca);
    atomicAdd(&u1[n + 256], ub); atomicAdd(&c1[n + 256], cb);
}

// ---- per-row LN stats (one wave per row, D=1024); optionally emit xb=bf16(x)
__global__ __launch_bounds__(256) void ln_stats_kernel(
    const float* __restrict__ x, float* __restrict__ mu, float* __restrict__ rs,
    unsigned short* __restrict__ xb) {
    const int D = 1024;
    int row = blockIdx.x * 4 + (threadIdx.x >> 6);
    int lane = threadIdx.x & 63;
    const float4* xr = (const float4*)(x + (size_t)row * D);
    float s = 0.f, ss = 0.f;
#pragma unroll
    for (int i = 0; i < 4; i++) {
        float4 v = xr[lane + 64 * i];
        s  += v.x + v.y + v.z + v.w;
        ss += v.x * v.x + v.y * v.y + v.z * v.z + v.w * v.w;
        if (xb) {
            ushort4v o;
            o.x = f2bf(v.x); o.y = f2bf(v.y); o.z = f2bf(v.z); o.w = f2bf(v.w);
            *(ushort4v*)(xb + (size_t)row * D + 4 * (lane + 64 * i)) = o;
        }
    }
#pragma unroll
    for (int off = 32; off; off >>= 1) {
        s  += __shfl_xor(s, off);
        ss += __shfl_xor(ss, off);
    }
    if (lane == 0) {
        float m = s * (1.0f / 1024.0f);
        mu[row] = m;
        rs[row] = rsqrtf(ss * (1.0f / 1024.0f) - m * m + 1e-5f);
    }
}

// ---- GEMM: C[M,N] = A[M,K] * Bt[N,K]^T, 128x128 tile, BK=32, 256 thr / 4 waves
// EPMODE 0: LN-corrected + gelu -> bf16
// EPMODE 1: +bias, gelu -> bf16
// EPMODE 2: +bias, +residual(fp32) -> fp32
// AF32: A is fp32, converted during manual staging (fallback when no xb space).
template <int EPMODE, bool AF32>
__global__ __launch_bounds__(256) void gemm_kernel(
    const void* __restrict__ Aptr, const unsigned short* __restrict__ Bt,
    void* __restrict__ Out, int N, int K,
    const float* __restrict__ bias,   // EP0: c1
    const float* __restrict__ u1,     // EP0 only
    const float* __restrict__ mu,     // EP0 only
    const float* __restrict__ rs,     // EP0 only
    const float* __restrict__ resid)  // EP2 only
{
    constexpr int BM = 128, BN = 128, BK = 32;
    __shared__ unsigned short As[BM][BK];
    __shared__ unsigned short Bs[BN][BK];

    const int tid  = threadIdx.x;
    const int wave = tid >> 6;
    const int lane = tid & 63;
    const int q    = lane >> 4;   // quad 0..3
    const int l16  = lane & 15;
    const int wm   = wave & 1;    // wave row-half
    const int wn   = wave >> 1;   // wave col-half
    const int m0   = blockIdx.y * BM;
    const int n0   = blockIdx.x * BN;

    // staging geometry: thread tid covers tile bytes [tid*16, tid*16+16)
    const int sr = tid >> 2;          // tile row 0..63 (chunk 0) / +64 (chunk 1)
    const int sc = tid & 3;           // 8-elem column group
    unsigned short* lA = &As[0][0] + ((tid >> 6) << 9);  // wave*1024 B
    unsigned short* lB = &Bs[0][0] + ((tid >> 6) << 9);
    const unsigned short* gb0 = Bt + (size_t)(n0 + sr) * K + sc * 8;
    const unsigned short* ga0 = nullptr;
    if (!AF32) ga0 = (const unsigned short*)Aptr + (size_t)(m0 + sr) * K + sc * 8;

    floatx4 acc[4][4] = {};

    for (int k0 = 0; k0 < K; k0 += BK) {
        if (AF32) {
            const float* A = (const float*)Aptr;
            int c = tid & 7, r0 = tid >> 3;            // c: float4 chunk, r0: 0..31
#pragma unroll
            for (int i = 0; i < 4; i++) {
                int r = r0 + 32 * i;
                float4 v = *(const float4*)(A + (size_t)(m0 + r) * K + k0 + c * 4);
                unsigned short* dst = &As[r][c * 4];
                dst[0] = f2bf(v.x); dst[1] = f2bf(v.y);
                dst[2] = f2bf(v.z); dst[3] = f2bf(v.w);
            }
        } else {
            gl_lds16(ga0 + k0, lA);
            gl_lds16(ga0 + k0 + (size_t)64 * K, lA + 2048);  // +4096 B
        }
        gl_lds16(gb0 + k0, lB);
        gl_lds16(gb0 + k0 + (size_t)64 * K, lB + 2048);
        __syncthreads();

        short8 a[4], b[4];
#pragma unroll
        for (int mt = 0; mt < 4; mt++)
            a[mt] = *(const short8*)&As[wm * 64 + mt * 16 + l16][q * 8];
#pragma unroll
        for (int nt = 0; nt < 4; nt++)
            b[nt] = *(const short8*)&Bs[wn * 64 + nt * 16 + l16][q * 8];
#pragma unroll
        for (int mt = 0; mt < 4; mt++)
#pragma unroll
            for (int nt = 0; nt < 4; nt++)
                acc[mt][nt] = __builtin_amdgcn_mfma_f32_16x16x32_bf16(
                    a[mt], b[nt], acc[mt][nt], 0, 0, 0);
        __syncthreads();
    }

    // ---- epilogue: C/D layout col = lane&15, row = quad*4 + reg
#pragma unroll
    for (int mt = 0; mt < 4; mt++) {
#pragma unroll
        for (int r = 0; r < 4; r++) {
            int row = m0 + wm * 64 + mt * 16 + q * 4 + r;
            float rsv = 0.f, muv = 0.f;
            if (EPMODE == 0) { rsv = rs[row]; muv = mu[row]; }
#pragma unroll
            for (int nt = 0; nt < 4; nt++) {
                int col = n0 + wn * 64 + nt * 16 + l16;
                float v = acc[mt][nt][r];
                if constexpr (EPMODE == 0) {
                    v = rsv * (v - muv * u1[col]) + bias[col];
                    v = gelu_exact(v);
                    ((unsigned short*)Out)[(size_t)row * N + col] = f2bf(v);
                } else if constexpr (EPMODE == 1) {
                    v = gelu_exact(v + bias[col]);
                    ((unsigned short*)Out)[(size_t)row * N + col] = f2bf(v);
                } else {
                    v = v + bias[col] + resid[(size_t)row * N + col];
                    ((float*)Out)[(size_t)row * N + col] = v;
                }
            }
        }
    }
}

extern "C" void kernel_launch(void* const* d_in, const int* in_sizes, int n_in,
                              void* d_out, int out_size, void* d_ws, size_t ws_size,
                              hipStream_t stream) {
    const float* x     = (const float*)d_in[0];
    const float* gamma = (const float*)d_in[1];
    const float* beta  = (const float*)d_in[2];
    const float* W1    = (const float*)d_in[3];
    const float* b1    = (const float*)d_in[4];
    const float* W2    = (const float*)d_in[5];
    const float* b2    = (const float*)d_in[6];
    const float* W3    = (const float*)d_in[7];
    const float* b3    = (const float*)d_in[8];
    const float* W4    = (const float*)d_in[9];
    const float* b4    = (const float*)d_in[10];
    float* out = (float*)d_out;

    const int D = 1024, H1 = 512, H2 = 512, H3 = 256;
    const int M = in_sizes[0] / D;   // 32768

    // ---- workspace layout (bytes, all 256-aligned) -------------------------
    char* ws = (char*)d_ws;
    unsigned short* Wt1 = (unsigned short*)(ws + 0);          // 512x1024 bf16, gamma-folded
    unsigned short* Wt2 = (unsigned short*)(ws + 1048576);    // 512x512
    unsigned short* Wt3 = (unsigned short*)(ws + 1572864);    // 256x512
    unsigned short* Wt4 = (unsigned short*)(ws + 1835008);    // 1024x256
    float* u1           = (float*)(ws + 2359296);             // [512]
    float* c1           = (float*)(ws + 2361344);             // [512]
    float* muv          = (float*)(ws + 2363392);             // [M]
    float* rsv          = (float*)(ws + 2494464);             // [M]
    unsigned short* h1  = (unsigned short*)(ws + 2625536);    // M x 512 bf16 (32MB)
    unsigned short* h2  = (unsigned short*)(ws + 36179968);   // M x 512 bf16 (32MB)
    unsigned short* h3  = h1;                                 // alias: h1 dead after G2
    size_t base_end     = 36179968 + (size_t)M * H2 * 2;      // ~69.7MB
    // optional xb = bf16(x), M x 1024 (64MB), enables lds-direct A for GEMM1
    unsigned short* xb  = (unsigned short*)(ws + base_end);
    bool use_xb = (ws_size >= base_end + (size_t)M * D * 2);

    // ---- weight prep -------------------------------------------------------
    conv_w_kernel<<<(D * H1 + 255) / 256, 256, 0, stream>>>(W1, gamma, Wt1, D,  H1);
    conv_w_kernel<<<(H1 * H2 + 255) / 256, 256, 0, stream>>>(W2, nullptr, Wt2, H1, H2);
    conv_w_kernel<<<(H2 * H3 + 255) / 256, 256, 0, stream>>>(W3, nullptr, Wt3, H2, H3);
    conv_w_kernel<<<(H3 * D + 255) / 256, 256, 0, stream>>>(W4, nullptr, Wt4, H3, D);
    u1c1_init_kernel<<<(H1 + 255) / 256, 256, 0, stream>>>(b1, u1, c1, H1);
    u1c1_kernel<<<D / 16, 256, 0, stream>>>(W1, gamma, beta, u1, c1);

    // ---- LN row stats (+ optional bf16 conversion of x) --------------------
    ln_stats_kernel<<<M / 4, 256, 0, stream>>>(x, muv, rsv, use_xb ? xb : nullptr);

    // ---- GEMM chain --------------------------------------------------------
    if (use_xb) {
        gemm_kernel<0, false><<<dim3(H1 / 128, M / 128), 256, 0, stream>>>(
            xb, Wt1, h1,  H1, D,  c1, u1, muv, rsv, nullptr);
    } else {
        gemm_kernel<0, true ><<<dim3(H1 / 128, M / 128), 256, 0, stream>>>(
            x,  Wt1, h1,  H1, D,  c1, u1, muv, rsv, nullptr);
    }
    gemm_kernel<1, false><<<dim3(H2 / 128, M / 128), 256, 0, stream>>>(
        h1, Wt2, h2,  H2, H1, b2, nullptr, nullptr, nullptr, nullptr);
    gemm_kernel<1, false><<<dim3(H3 / 128, M / 128), 256, 0, stream>>>(
        h2, Wt3, h3,  H3, H2, b3, nullptr, nullptr, nullptr, nullptr);
    gemm_kernel<2, false><<<dim3(D  / 128, M / 128), 256, 0, stream>>>(
        h3, Wt4, out, D,  H3, b4, nullptr, nullptr, nullptr, x);
}

// Round 3
// 426.210 us; speedup vs baseline: 1.6302x; 1.1058x over previous
//
#include <hip/hip_runtime.h>

// ---------------------------------------------------------------------------
// FDA_Module_21500606283969: out = x + MLP(LN(x))
// R3: (a) fast tanh-GELU (exp2+rcp, ~9 VALU ops) replacing erff (~30+) — the
//         epilogue VALU cost exceeded the whole K-loop MFMA cost (MfmaUtil 15%
//         vs VALUBusy 38%),
//     (b) XCD-aware block swizzle: same-A-panel n-blocks run consecutively on
//         one XCD -> A fetched once (GEMM1 FETCH was 134MB vs 65MB ideal),
//     (c) GEMM4 residual read from xb (bf16) -64MB HBM; fused weight-prep.
// ---------------------------------------------------------------------------

typedef short short8 __attribute__((ext_vector_type(8)));
typedef float floatx4 __attribute__((ext_vector_type(4)));
typedef unsigned short ushort4v __attribute__((ext_vector_type(4)));

__device__ __forceinline__ unsigned short f2bf(float f) {
    union { float f; unsigned int u; } a; a.f = f;
    unsigned int u = a.u;
    return (unsigned short)((u + 0x7FFFu + ((u >> 16) & 1u)) >> 16);
}

__device__ __forceinline__ float bf2f(unsigned short h) {
    union { unsigned int u; float f; } a; a.u = ((unsigned int)h) << 16;
    return a.f;
}

// tanh-approx GELU; |err vs exact erf-GELU| <~ 1e-4 over the h-range here,
// far below bf16 rounding. ~9 VALU ops (1 v_exp_f32 + 1 v_rcp_f32 + FMAs).
__device__ __forceinline__ float gelu_fast(float v) {
    float u = 0.7978845608f * v * (1.0f + 0.044715f * v * v);
    float e = __builtin_amdgcn_exp2f(u * 2.885390082f);      // exp(2u)
    float t = 1.0f - 2.0f * __builtin_amdgcn_rcpf(1.0f + e); // tanh(u)
    return 0.5f * v * (1.0f + t);
}

// async global->LDS, 16B per lane; LDS dst = wave-uniform base + lane*16
__device__ __forceinline__ void gl_lds16(const unsigned short* g, unsigned short* l) {
    __builtin_amdgcn_global_load_lds(
        (const __attribute__((address_space(1))) void*)g,
        (__attribute__((address_space(3))) void*)l, 16, 0, 0);
}

// ---- fused weight transpose+convert for all four weights (one launch)
// Wt[n*K+k] = bf16(W[k*N+n] * (scale?scale[k]:1))
__global__ __launch_bounds__(256) void conv_all_kernel(
    const float* __restrict__ W1, const float* __restrict__ W2,
    const float* __restrict__ W3, const float* __restrict__ W4,
    const float* __restrict__ gamma,
    unsigned short* __restrict__ Wt1, unsigned short* __restrict__ Wt2,
    unsigned short* __restrict__ Wt3, unsigned short* __restrict__ Wt4) {
    int b = blockIdx.x;
    const float* W; unsigned short* Wt; int K, N; const float* sc = nullptr;
    if (b < 2048)      { W = W1; Wt = Wt1; K = 1024; N = 512;  sc = gamma; }
    else if (b < 3072) { W = W2; Wt = Wt2; K = 512;  N = 512;  b -= 2048; }
    else if (b < 3584) { W = W3; Wt = Wt3; K = 512;  N = 256;  b -= 3072; }
    else               { W = W4; Wt = Wt4; K = 256;  N = 1024; b -= 3584; }
    int t = b * 256 + threadIdx.x;          // t = k*N + n (coalesced read)
    int sh = 31 - __clz(N);                 // N is a power of two
    int k = t >> sh, n = t & (N - 1);
    float v = W[t];
    if (sc) v *= sc[k];
    Wt[(size_t)n * K + k] = f2bf(v);
}

// ---- u1[n]=0 ; c1[n]=b1[n]  (seed for atomic accumulation)
__global__ __launch_bounds__(256) void u1c1_init_kernel(
    const float* __restrict__ b1, float* __restrict__ u1, float* __restrict__ c1,
    int N) {
    int n = blockIdx.x * 256 + threadIdx.x;
    if (n >= N) return;
    u1[n] = 0.f;
    c1[n] = b1[n];
}

// ---- partial u1/c1: block b covers k in [b*16, b*16+16), thread -> cols n, n+256
__global__ __launch_bounds__(256) void u1c1_kernel(
    const float* __restrict__ W1, const float* __restrict__ gamma,
    const float* __restrict__ beta, float* __restrict__ u1,
    float* __restrict__ c1) {
    const int N = 512;
    __shared__ float gs[16], bs[16];
    int n = threadIdx.x;
    int k0 = blockIdx.x * 16;
    if (n < 16) { gs[n] = gamma[k0 + n]; bs[n] = beta[k0 + n]; }
    __syncthreads();
    float ua = 0.f, ca = 0.f, ub = 0.f, cb = 0.f;
#pragma unroll
    for (int i = 0; i < 16; i++) {
        float w0 = W1[(size_t)(k0 + i) * N + n];
        float w1 = W1[(size_t)(k0 + i) * N + n + 256];
        ua += gs[i] * w0; ca += bs[i] * w0;
        ub += gs[i] * w1; cb += bs[i] * w1;
    }
    atomicAdd(&u1[n], ua);       atomicAdd(&c1[n], ca);
    atomicAdd(&u1[n + 256], ub); atomicAdd(&c1[n + 256], cb);
}

// ---- per-row LN stats (one wave per row, D=1024); optionally emit xb=bf16(x)
__global__ __launch_bounds__(256) void ln_stats_kernel(
    const float* __restrict__ x, float* __restrict__ mu, float* __restrict__ rs,
    unsigned short* __restrict__ xb) {
    const int D = 1024;
    int row = blockIdx.x * 4 + (threadIdx.x >> 6);
    int lane = threadIdx.x & 63;
    const float4* xr = (const float4*)(x + (size_t)row * D);
    float s = 0.f, ss = 0.f;
#pragma unroll
    for (int i = 0; i < 4; i++) {
        float4 v = xr[lane + 64 * i];
        s  += v.x + v.y + v.z + v.w;
        ss += v.x * v.x + v.y * v.y + v.z * v.z + v.w * v.w;
        if (xb) {
            ushort4v o;
            o.x = f2bf(v.x); o.y = f2bf(v.y); o.z = f2bf(v.z); o.w = f2bf(v.w);
            *(ushort4v*)(xb + (size_t)row * D + 4 * (lane + 64 * i)) = o;
        }
    }
#pragma unroll
    for (int off = 32; off; off >>= 1) {
        s  += __shfl_xor(s, off);
        ss += __shfl_xor(ss, off);
    }
    if (lane == 0) {
        float m = s * (1.0f / 1024.0f);
        mu[row] = m;
        rs[row] = rsqrtf(ss * (1.0f / 1024.0f) - m * m + 1e-5f);
    }
}

// ---- GEMM: C[M,N] = A[M,K] * Bt[N,K]^T, 128x128 tile, BK=32, 256 thr / 4 waves
// 1D grid of NBN*NBM blocks; XCD swizzle: blocks with the same A row-panel run
// in consecutive slots on the same XCD (id%8 heuristic) for L2 A-reuse.
// EPMODE 0: LN-corrected + gelu -> bf16
// EPMODE 1: +bias, gelu -> bf16
// EPMODE 2: +bias, +residual(fp32) -> fp32
// EPMODE 3: +bias, +residual(bf16) -> fp32
template <int EPMODE, bool AF32, int NBN>
__global__ __launch_bounds__(256) void gemm_kernel(
    const void* __restrict__ Aptr, const unsigned short* __restrict__ Bt,
    void* __restrict__ Out, int N, int K,
    const float* __restrict__ bias,   // EP0: c1
    const float* __restrict__ u1,     // EP0 only
    const float* __restrict__ mu,     // EP0 only
    const float* __restrict__ rs,     // EP0 only
    const void* __restrict__ resid)   // EP2/EP3 only
{
    constexpr int BM = 128, BN = 128, BK = 32;
    __shared__ unsigned short As[BM][BK];
    __shared__ unsigned short Bs[BN][BK];

    const int tid  = threadIdx.x;
    const int wave = tid >> 6;
    const int lane = tid & 63;
    const int q    = lane >> 4;   // quad 0..3
    const int l16  = lane & 15;
    const int wm   = wave & 1;    // wave row-half
    const int wn   = wave >> 1;   // wave col-half

    // XCD-aware swizzle
    const int id   = blockIdx.x;
    const int xcd  = id & 7;
    const int slot = id >> 3;
    const int m0   = (xcd + 8 * (slot / NBN)) * BM;
    const int n0   = (slot % NBN) * BN;

    // staging geometry: thread tid covers tile bytes [tid*16, tid*16+16)
    const int sr = tid >> 2;          // tile row 0..63 (chunk 0) / +64 (chunk 1)
    const int sc = tid & 3;           // 8-elem column group
    unsigned short* lA = &As[0][0] + (wave << 9);  // wave*1024 B
    unsigned short* lB = &Bs[0][0] + (wave << 9);
    const unsigned short* gb0 = Bt + (size_t)(n0 + sr) * K + sc * 8;
    const unsigned short* ga0 = nullptr;
    if (!AF32) ga0 = (const unsigned short*)Aptr + (size_t)(m0 + sr) * K + sc * 8;

    floatx4 acc[4][4] = {};

    for (int k0 = 0; k0 < K; k0 += BK) {
        if (AF32) {
            const float* A = (const float*)Aptr;
            int c = tid & 7, r0 = tid >> 3;            // c: float4 chunk, r0: 0..31
#pragma unroll
            for (int i = 0; i < 4; i++) {
                int r = r0 + 32 * i;
                float4 v = *(const float4*)(A + (size_t)(m0 + r) * K + k0 + c * 4);
                unsigned short* dst = &As[r][c * 4];
                dst[0] = f2bf(v.x); dst[1] = f2bf(v.y);
                dst[2] = f2bf(v.z); dst[3] = f2bf(v.w);
            }
        } else {
            gl_lds16(ga0 + k0, lA);
            gl_lds16(ga0 + k0 + (size_t)64 * K, lA + 2048);  // +4096 B
        }
        gl_lds16(gb0 + k0, lB);
        gl_lds16(gb0 + k0 + (size_t)64 * K, lB + 2048);
        __syncthreads();

        short8 a[4], b[4];
#pragma unroll
        for (int mt = 0; mt < 4; mt++)
            a[mt] = *(const short8*)&As[wm * 64 + mt * 16 + l16][q * 8];
#pragma unroll
        for (int nt = 0; nt < 4; nt++)
            b[nt] = *(const short8*)&Bs[wn * 64 + nt * 16 + l16][q * 8];
#pragma unroll
        for (int mt = 0; mt < 4; mt++)
#pragma unroll
            for (int nt = 0; nt < 4; nt++)
                acc[mt][nt] = __builtin_amdgcn_mfma_f32_16x16x32_bf16(
                    a[mt], b[nt], acc[mt][nt], 0, 0, 0);
        __syncthreads();
    }

    // ---- epilogue: C/D layout col = lane&15, row = quad*4 + reg
#pragma unroll
    for (int nt = 0; nt < 4; nt++) {
        const int col = n0 + wn * 64 + nt * 16 + l16;
        const float bv = bias[col];
        const float uv = (EPMODE == 0) ? u1[col] : 0.f;
#pragma unroll
        for (int mt = 0; mt < 4; mt++) {
#pragma unroll
            for (int r = 0; r < 4; r++) {
                const int row = m0 + wm * 64 + mt * 16 + q * 4 + r;
                float v = acc[mt][nt][r];
                if constexpr (EPMODE == 0) {
                    v = rs[row] * (v - mu[row] * uv) + bv;
                    v = gelu_fast(v);
                    ((unsigned short*)Out)[(size_t)row * N + col] = f2bf(v);
                } else if constexpr (EPMODE == 1) {
                    v = gelu_fast(v + bv);
                    ((unsigned short*)Out)[(size_t)row * N + col] = f2bf(v);
                } else if constexpr (EPMODE == 2) {
                    v = v + bv + ((const float*)resid)[(size_t)row * N + col];
                    ((float*)Out)[(size_t)row * N + col] = v;
                } else {
                    v = v + bv + bf2f(((const unsigned short*)resid)[(size_t)row * N + col]);
                    ((float*)Out)[(size_t)row * N + col] = v;
                }
            }
        }
    }
}

extern "C" void kernel_launch(void* const* d_in, const int* in_sizes, int n_in,
                              void* d_out, int out_size, void* d_ws, size_t ws_size,
                              hipStream_t stream) {
    const float* x     = (const float*)d_in[0];
    const float* gamma = (const float*)d_in[1];
    const float* beta  = (const float*)d_in[2];
    const float* W1    = (const float*)d_in[3];
    const float* b1    = (const float*)d_in[4];
    const float* W2    = (const float*)d_in[5];
    const float* b2    = (const float*)d_in[6];
    const float* W3    = (const float*)d_in[7];
    const float* b3    = (const float*)d_in[8];
    const float* W4    = (const float*)d_in[9];
    const float* b4    = (const float*)d_in[10];
    float* out = (float*)d_out;

    const int D = 1024, H1 = 512, H2 = 512, H3 = 256;
    const int M = in_sizes[0] / D;   // 32768

    // ---- workspace layout (bytes, all 256-aligned) -------------------------
    char* ws = (char*)d_ws;
    unsigned short* Wt1 = (unsigned short*)(ws + 0);          // 512x1024 bf16, gamma-folded
    unsigned short* Wt2 = (unsigned short*)(ws + 1048576);    // 512x512
    unsigned short* Wt3 = (unsigned short*)(ws + 1572864);    // 256x512
    unsigned short* Wt4 = (unsigned short*)(ws + 1835008);    // 1024x256
    float* u1           = (float*)(ws + 2359296);             // [512]
    float* c1           = (float*)(ws + 2361344);             // [512]
    float* muv          = (float*)(ws + 2363392);             // [M]
    float* rsv          = (float*)(ws + 2494464);             // [M]
    unsigned short* h1  = (unsigned short*)(ws + 2625536);    // M x 512 bf16 (32MB)
    unsigned short* h2  = (unsigned short*)(ws + 36179968);   // M x 512 bf16 (32MB)
    unsigned short* h3  = h1;                                 // alias: h1 dead after G2
    size_t base_end     = 36179968 + (size_t)M * H2 * 2;      // ~69.7MB
    // optional xb = bf16(x), M x 1024 (64MB): lds-direct A for GEMM1 + bf16 residual
    unsigned short* xb  = (unsigned short*)(ws + base_end);
    bool use_xb = (ws_size >= base_end + (size_t)M * D * 2);

    const int NBM = M / 128;   // 256

    // ---- weight prep (one fused launch) ------------------------------------
    conv_all_kernel<<<4608, 256, 0, stream>>>(W1, W2, W3, W4, gamma,
                                              Wt1, Wt2, Wt3, Wt4);
    u1c1_init_kernel<<<(H1 + 255) / 256, 256, 0, stream>>>(b1, u1, c1, H1);
    u1c1_kernel<<<D / 16, 256, 0, stream>>>(W1, gamma, beta, u1, c1);

    // ---- LN row stats (+ bf16 conversion of x) -----------------------------
    ln_stats_kernel<<<M / 4, 256, 0, stream>>>(x, muv, rsv, use_xb ? xb : nullptr);

    // ---- GEMM chain --------------------------------------------------------
    if (use_xb) {
        gemm_kernel<0, false, 4><<<4 * NBM, 256, 0, stream>>>(
            xb, Wt1, h1,  H1, D,  c1, u1, muv, rsv, nullptr);
    } else {
        gemm_kernel<0, true, 4><<<4 * NBM, 256, 0, stream>>>(
            x,  Wt1, h1,  H1, D,  c1, u1, muv, rsv, nullptr);
    }
    gemm_kernel<1, false, 4><<<4 * NBM, 256, 0, stream>>>(
        h1, Wt2, h2,  H2, H1, b2, nullptr, nullptr, nullptr, nullptr);
    gemm_kernel<1, false, 2><<<2 * NBM, 256, 0, stream>>>(
        h2, Wt3, h3,  H3, H2, b3, nullptr, nullptr, nullptr, nullptr);
    if (use_xb) {
        gemm_kernel<3, false, 8><<<8 * NBM, 256, 0, stream>>>(
            h3, Wt4, out, D,  H3, b4, nullptr, nullptr, nullptr, xb);
    } else {
        gemm_kernel<2, false, 8><<<8 * NBM, 256, 0, stream>>>(
            h3, Wt4, out, D,  H3, b4, nullptr, nullptr, nullptr, x);
    }
}